// Round 1
// baseline (9808.598 us; speedup 1.0000x reference)
//
#include <hip/hip_runtime.h>
#include <hip/hip_bf16.h>
#include <cstdint>
#include <cstddef>

#define B_ROWS 16384
#define DIM    768
#define HID    16384
#define BM     128
#define BN     128
#define BK     16
#define NCB    (HID / BN)   // 128 column blocks

// ---------- top-3 helpers (tie-break: lower index wins, matching jax.lax.top_k) ----------
__device__ __forceinline__ bool better(float v1, int i1, float v2, int i2) {
    return (v1 > v2) || (v1 == v2 && i1 < i2);
}

__device__ __forceinline__ void ins3(float v, int i,
                                     float& v0, int& i0,
                                     float& v1, int& i1,
                                     float& v2, int& i2) {
    if (better(v, i, v2, i2)) {
        v2 = v; i2 = i;
        if (better(v2, i2, v1, i1)) { float tv = v1; int ti = i1; v1 = v2; i1 = i2; v2 = tv; i2 = ti; }
        if (better(v1, i1, v0, i0)) { float tv = v0; int ti = i0; v0 = v1; i0 = i1; v1 = tv; i1 = ti; }
    }
}

// ---------- fused encoder GEMM + per-(row, colblock) top-3 ----------
// X: [B, DIM] row-major, W: [HID, DIM] row-major (so X @ W^T needs dot of rows)
// pv/pi: [B][NCB][3] partial top-3 values / indices
__global__ __launch_bounds__(256) void gemm_topk(
        const float* __restrict__ X, const float* __restrict__ W,
        const float* __restrict__ benc,
        float* __restrict__ pv, int* __restrict__ pi) {
    __shared__ float As[BK][BM + 4];   // +4 pad keeps 16B alignment, 2-way bank alias only (free)
    __shared__ float Bs[BK][BN + 4];

    const int cb  = blockIdx.x;
    const int rb  = blockIdx.y;
    const int tid = threadIdx.x;
    const int tx  = tid & 15;          // col group
    const int ty  = tid >> 4;          // row group
    const int rowBase = rb * BM;
    const int colBase = cb * BN;

    const float* Ap = X + (size_t)rowBase * DIM;
    const float* Bp = W + (size_t)colBase * DIM;

    float acc[8][8];
#pragma unroll
    for (int i = 0; i < 8; i++)
#pragma unroll
        for (int j = 0; j < 8; j++) acc[i][j] = 0.0f;

    for (int k0 = 0; k0 < DIM; k0 += BK) {
        // stage A/B tiles: 128 rows x 16 k-floats each; 2 float4 per thread per tile
#pragma unroll
        for (int i = 0; i < 2; i++) {
            const int v  = tid + i * 256;
            const int r  = v >> 2;
            const int kv = v & 3;
            const float4 fa = *(const float4*)(Ap + (size_t)r * DIM + k0 + kv * 4);
            const float4 fb = *(const float4*)(Bp + (size_t)r * DIM + k0 + kv * 4);
            const int kk = kv * 4;
            As[kk + 0][r] = fa.x; As[kk + 1][r] = fa.y; As[kk + 2][r] = fa.z; As[kk + 3][r] = fa.w;
            Bs[kk + 0][r] = fb.x; Bs[kk + 1][r] = fb.y; Bs[kk + 2][r] = fb.z; Bs[kk + 3][r] = fb.w;
        }
        __syncthreads();

#pragma unroll
        for (int k = 0; k < BK; k++) {
            const float4 a0 = *(const float4*)&As[k][ty * 8];
            const float4 a1 = *(const float4*)&As[k][ty * 8 + 4];
            const float4 b0 = *(const float4*)&Bs[k][tx * 8];
            const float4 b1 = *(const float4*)&Bs[k][tx * 8 + 4];
            const float av[8] = {a0.x, a0.y, a0.z, a0.w, a1.x, a1.y, a1.z, a1.w};
            const float bv[8] = {b0.x, b0.y, b0.z, b0.w, b1.x, b1.y, b1.z, b1.w};
#pragma unroll
            for (int i = 0; i < 8; i++)
#pragma unroll
                for (int j = 0; j < 8; j++)
                    acc[i][j] = fmaf(av[i], bv[j], acc[i][j]);
        }
        __syncthreads();
    }

    // epilogue: add b_enc, per-row top-3 within this 128-col block
    float bv[8];
#pragma unroll
    for (int j = 0; j < 8; j++) bv[j] = benc[colBase + tx * 8 + j];

    for (int i = 0; i < 8; i++) {
        float v0 = -INFINITY, v1 = -INFINITY, v2 = -INFINITY;
        int   i0 = 0x7fffffff, i1 = 0x7fffffff, i2 = 0x7fffffff;
#pragma unroll
        for (int j = 0; j < 8; j++) {
            const float v  = acc[i][j] + bv[j];
            const int  idx = colBase + tx * 8 + j;
            ins3(v, idx, v0, i0, v1, i1, v2, i2);
        }
        // merge across the 16 lanes sharing this row group (masks < 16 stay in-group)
#pragma unroll
        for (int m = 1; m < 16; m <<= 1) {
            const float w0 = __shfl_xor(v0, m, 64);
            const float w1 = __shfl_xor(v1, m, 64);
            const float w2 = __shfl_xor(v2, m, 64);
            const int   j0 = __shfl_xor(i0, m, 64);
            const int   j1 = __shfl_xor(i1, m, 64);
            const int   j2 = __shfl_xor(i2, m, 64);
            ins3(w0, j0, v0, i0, v1, i1, v2, i2);
            ins3(w1, j1, v0, i0, v1, i1, v2, i2);
            ins3(w2, j2, v0, i0, v1, i1, v2, i2);
        }
        if (tx == 0) {
            const int row = rowBase + ty * 8 + i;
            const size_t base = ((size_t)row * NCB + cb) * 3;
            pv[base + 0] = v0; pv[base + 1] = v1; pv[base + 2] = v2;
            pi[base + 0] = i0; pi[base + 1] = i1; pi[base + 2] = i2;
        }
    }
}

// ---------- reduce partial top-3 over 128 colblocks -> final top-3 per row ----------
__global__ __launch_bounds__(64) void reduce_topk(
        const float* __restrict__ pv, const int* __restrict__ pi,
        float* __restrict__ fv, int* __restrict__ fi, int* __restrict__ mask) {
    const int row  = blockIdx.x;
    const int lane = threadIdx.x;  // 64
    float v0 = -INFINITY, v1 = -INFINITY, v2 = -INFINITY;
    int   i0 = 0x7fffffff, i1 = 0x7fffffff, i2 = 0x7fffffff;
    for (int c = lane; c < NCB; c += 64) {
        const size_t base = ((size_t)row * NCB + c) * 3;
#pragma unroll
        for (int t = 0; t < 3; t++)
            ins3(pv[base + t], pi[base + t], v0, i0, v1, i1, v2, i2);
    }
#pragma unroll
    for (int m = 1; m < 64; m <<= 1) {
        const float w0 = __shfl_xor(v0, m, 64);
        const float w1 = __shfl_xor(v1, m, 64);
        const float w2 = __shfl_xor(v2, m, 64);
        const int   j0 = __shfl_xor(i0, m, 64);
        const int   j1 = __shfl_xor(i1, m, 64);
        const int   j2 = __shfl_xor(i2, m, 64);
        ins3(w0, j0, v0, i0, v1, i1, v2, i2);
        ins3(w1, j1, v0, i0, v1, i1, v2, i2);
        ins3(w2, j2, v0, i0, v1, i1, v2, i2);
    }
    if (lane == 0) {
        fv[row * 3 + 0] = v0; fv[row * 3 + 1] = v1; fv[row * 3 + 2] = v2;
        fi[row * 3 + 0] = i0; fi[row * 3 + 1] = i1; fi[row * 3 + 2] = i2;
        mask[i0] = 1; mask[i1] = 1; mask[i2] = 1;   // idempotent racy stores, fine
    }
}

// ---------- count live latents ----------
__global__ __launch_bounds__(256) void count_live(const int* __restrict__ mask,
                                                  float* __restrict__ outScalar) {
    __shared__ int sd[256];
    const int tid = threadIdx.x;
    int s = 0;
    for (int i = tid; i < HID; i += 256) s += mask[i];
    sd[tid] = s;
    __syncthreads();
    for (int st = 128; st > 0; st >>= 1) {
        if (tid < st) sd[tid] += sd[tid + st];
        __syncthreads();
    }
    if (tid == 0) outScalar[0] = (float)sd[0];
}

// ---------- transpose W_dec [DIM][HID] -> Wt [HID][DIM] so decode gathers are coalesced ----------
__global__ __launch_bounds__(256) void transpose_wdec(const float* __restrict__ W,
                                                      float* __restrict__ Wt) {
    __shared__ float t[32][33];
    const int bx = blockIdx.x;          // along HID (16384/32)
    const int by = blockIdx.y;          // along DIM (768/32)
    const int x  = threadIdx.x & 31;
    const int y  = threadIdx.x >> 5;    // 0..7
#pragma unroll
    for (int i = 0; i < 4; i++) {
        const int d = by * 32 + y + i * 8;
        t[y + i * 8][x] = W[(size_t)d * HID + bx * 32 + x];
    }
    __syncthreads();
#pragma unroll
    for (int i = 0; i < 4; i++) {
        const int h = bx * 32 + y + i * 8;
        Wt[(size_t)h * DIM + by * 32 + x] = t[x][y + i * 8];
    }
}

// ---------- sparse decode: out[b,:] = b_dec + sum_k val_k * Wt[idx_k,:] ----------
__global__ __launch_bounds__(192) void decode_rows(
        const float* __restrict__ fv, const int* __restrict__ fi,
        const float* __restrict__ Wt, const float* __restrict__ bdec,
        float* __restrict__ out) {
    const int row = blockIdx.x;
    const int tid = threadIdx.x;        // 192 threads * float4 = 768
    const float v0 = fv[row * 3 + 0], v1 = fv[row * 3 + 1], v2 = fv[row * 3 + 2];
    const int   i0 = fi[row * 3 + 0], i1 = fi[row * 3 + 1], i2 = fi[row * 3 + 2];
    const int j = tid * 4;
    const float4 b  = *(const float4*)(bdec + j);
    const float4 w0 = *(const float4*)(Wt + (size_t)i0 * DIM + j);
    const float4 w1 = *(const float4*)(Wt + (size_t)i1 * DIM + j);
    const float4 w2 = *(const float4*)(Wt + (size_t)i2 * DIM + j);
    float4 o;
    o.x = b.x + v0 * w0.x + v1 * w1.x + v2 * w2.x;
    o.y = b.y + v0 * w0.y + v1 * w1.y + v2 * w2.y;
    o.z = b.z + v0 * w0.z + v1 * w1.z + v2 * w2.z;
    o.w = b.w + v0 * w0.w + v1 * w1.w + v2 * w2.w;
    *(float4*)(out + (size_t)row * DIM + j) = o;
}

extern "C" void kernel_launch(void* const* d_in, const int* in_sizes, int n_in,
                              void* d_out, int out_size, void* d_ws, size_t ws_size,
                              hipStream_t stream) {
    const float* X    = (const float*)d_in[0];   // [B, DIM]
    const float* Wenc = (const float*)d_in[1];   // [HID, DIM]
    const float* benc = (const float*)d_in[2];   // [HID]
    const float* Wdec = (const float*)d_in[3];   // [DIM, HID]
    const float* bdec = (const float*)d_in[4];   // [DIM]
    float* out = (float*)d_out;                  // [B*DIM] recon + [1] num_live (as float)

    // workspace layout (bytes):
    //   [0, 25165824)           pv  (B*NCB*3 floats)
    //   [25165824, 50331648)    pi  (B*NCB*3 ints)
    //   [0, 50331648)           Wt  (HID*DIM floats) -- REUSES pv+pi after reduce_topk
    //   [50331648, +196608)     fv  (B*3 floats)
    //   [50528256, +196608)     fi  (B*3 ints)
    //   [50724864, +65536)      mask (HID ints)
    char* ws = (char*)d_ws;
    float* pv   = (float*)ws;
    int*   pi   = (int*)(ws + 25165824);
    float* Wt   = (float*)ws;
    float* fv   = (float*)(ws + 50331648);
    int*   fi   = (int*)(ws + 50528256);
    int*   mask = (int*)(ws + 50724864);

    hipMemsetAsync(mask, 0, HID * sizeof(int), stream);

    gemm_topk<<<dim3(NCB, B_ROWS / BM), 256, 0, stream>>>(X, Wenc, benc, pv, pi);
    reduce_topk<<<B_ROWS, 64, 0, stream>>>(pv, pi, fv, fi, mask);
    count_live<<<1, 256, 0, stream>>>(mask, out + (size_t)B_ROWS * DIM);
    // transpose reuses pv/pi memory -> must come after reduce_topk (stream-ordered)
    transpose_wdec<<<dim3(HID / 32, DIM / 32), 256, 0, stream>>>(Wdec, Wt);
    decode_rows<<<B_ROWS, 192, 0, stream>>>(fv, fi, Wt, bdec, out);
}

// Round 2
// 4880.244 us; speedup vs baseline: 2.0099x; 2.0099x over previous
//
#include <hip/hip_runtime.h>
#include <hip/hip_bf16.h>
#include <cstdint>
#include <cstddef>

#define B_ROWS 16384
#define DIM    768
#define HID    16384
#define BM     128
#define BN     128
#define BK     16
#define NCB    (HID / BN)   // 128 column blocks

// ---------- top-3 helpers (tie-break: lower index wins, matching jax.lax.top_k) ----------
__device__ __forceinline__ bool better(float v1, int i1, float v2, int i2) {
    return (v1 > v2) || (v1 == v2 && i1 < i2);
}

__device__ __forceinline__ void ins3(float v, int i,
                                     float& v0, int& i0,
                                     float& v1, int& i1,
                                     float& v2, int& i2) {
    if (better(v, i, v2, i2)) {
        v2 = v; i2 = i;
        if (better(v2, i2, v1, i1)) { float tv = v1; int ti = i1; v1 = v2; i1 = i2; v2 = tv; i2 = ti; }
        if (better(v1, i1, v0, i0)) { float tv = v0; int ti = i0; v0 = v1; i0 = i1; v1 = tv; i1 = ti; }
    }
}

// ---------- fused encoder GEMM + per-(row, colblock) top-3 ----------
// X: [B, DIM] row-major, W: [HID, DIM] row-major (so X @ W^T needs dot of rows)
// pv/pi: [B][NCB][3] partial top-3 values / indices
// Thread (tx,ty), tx=tid&15, ty=tid>>4: rows ty*8+[0..8), cols {tx*4+[0..4), 64+tx*4+[0..4)}.
// Col split into two stride-4 runs: B-frag ds_read_b128 at tx*4 floats covers all 32 banks
// across 16 lanes with only 2-way distinct-address aliasing (free per m136); contiguous
// tx*8 mapping was a 4-way conflict (SQ_LDS_BANK_CONFLICT=5e8 in round 1).
__global__ __launch_bounds__(256) void gemm_topk(
        const float* __restrict__ X, const float* __restrict__ W,
        const float* __restrict__ benc,
        float* __restrict__ pv, int* __restrict__ pi) {
    __shared__ float As[BK][BM + 4];
    __shared__ float Bs[BK][BN + 4];

    const int cb  = blockIdx.x;
    const int rb  = blockIdx.y;
    const int tid = threadIdx.x;
    const int tx  = tid & 15;          // col group
    const int ty  = tid >> 4;          // row group
    const int rowBase = rb * BM;
    const int colBase = cb * BN;

    const float* Ap = X + (size_t)rowBase * DIM;
    const float* Bp = W + (size_t)colBase * DIM;

    float acc[8][8];   // [row i][col j]; j<4 -> col tx*4+j, j>=4 -> col 64+tx*4+(j-4)
#pragma unroll
    for (int i = 0; i < 8; i++)
#pragma unroll
        for (int j = 0; j < 8; j++) acc[i][j] = 0.0f;

    for (int k0 = 0; k0 < DIM; k0 += BK) {
        // stage A/B tiles: 128 rows x 16 k-floats each; 2 float4 per thread per tile
#pragma unroll
        for (int i = 0; i < 2; i++) {
            const int v  = tid + i * 256;
            const int r  = v >> 2;
            const int kv = v & 3;
            const float4 fa = *(const float4*)(Ap + (size_t)r * DIM + k0 + kv * 4);
            const float4 fb = *(const float4*)(Bp + (size_t)r * DIM + k0 + kv * 4);
            const int kk = kv * 4;
            As[kk + 0][r] = fa.x; As[kk + 1][r] = fa.y; As[kk + 2][r] = fa.z; As[kk + 3][r] = fa.w;
            Bs[kk + 0][r] = fb.x; Bs[kk + 1][r] = fb.y; Bs[kk + 2][r] = fb.z; Bs[kk + 3][r] = fb.w;
        }
        __syncthreads();

#pragma unroll
        for (int k = 0; k < BK; k++) {
            const float4 a0 = *(const float4*)&As[k][ty * 8];        // broadcast across tx (free)
            const float4 a1 = *(const float4*)&As[k][ty * 8 + 4];
            const float4 b0 = *(const float4*)&Bs[k][tx * 4];        // stride-4: conflict-free
            const float4 b1 = *(const float4*)&Bs[k][64 + tx * 4];
            const float av[8] = {a0.x, a0.y, a0.z, a0.w, a1.x, a1.y, a1.z, a1.w};
            const float bv[8] = {b0.x, b0.y, b0.z, b0.w, b1.x, b1.y, b1.z, b1.w};
#pragma unroll
            for (int i = 0; i < 8; i++)
#pragma unroll
                for (int j = 0; j < 8; j++)
                    acc[i][j] = fmaf(av[i], bv[j], acc[i][j]);
        }
        __syncthreads();
    }

    // epilogue: add b_enc, per-row top-3 within this 128-col block.
    // FULLY UNROLLED: runtime indexing into acc[][] forces it to scratch (round-1 bug:
    // 51 GB WRITE_SIZE, VGPR_Count=72 -> whole accumulator spilled).
    int bcol[8];
    float bv[8];
#pragma unroll
    for (int j = 0; j < 8; j++) {
        bcol[j] = colBase + (j < 4 ? tx * 4 + j : 64 + tx * 4 + (j - 4));
        bv[j] = benc[bcol[j]];
    }

#pragma unroll
    for (int i = 0; i < 8; i++) {
        float v0 = -INFINITY, v1 = -INFINITY, v2 = -INFINITY;
        int   i0 = 0x7fffffff, i1 = 0x7fffffff, i2 = 0x7fffffff;
#pragma unroll
        for (int j = 0; j < 8; j++) {
            const float v = acc[i][j] + bv[j];
            ins3(v, bcol[j], v0, i0, v1, i1, v2, i2);
        }
        // merge across the 16 lanes sharing this row group (masks < 16 stay in-group)
#pragma unroll
        for (int m = 1; m < 16; m <<= 1) {
            const float w0 = __shfl_xor(v0, m, 64);
            const float w1 = __shfl_xor(v1, m, 64);
            const float w2 = __shfl_xor(v2, m, 64);
            const int   j0 = __shfl_xor(i0, m, 64);
            const int   j1 = __shfl_xor(i1, m, 64);
            const int   j2 = __shfl_xor(i2, m, 64);
            ins3(w0, j0, v0, i0, v1, i1, v2, i2);
            ins3(w1, j1, v0, i0, v1, i1, v2, i2);
            ins3(w2, j2, v0, i0, v1, i1, v2, i2);
        }
        if (tx == 0) {
            const int row = rowBase + ty * 8 + i;
            const size_t base = ((size_t)row * NCB + cb) * 3;
            pv[base + 0] = v0; pv[base + 1] = v1; pv[base + 2] = v2;
            pi[base + 0] = i0; pi[base + 1] = i1; pi[base + 2] = i2;
        }
    }
}

// ---------- reduce partial top-3 over 128 colblocks -> final top-3 per row ----------
__global__ __launch_bounds__(64) void reduce_topk(
        const float* __restrict__ pv, const int* __restrict__ pi,
        float* __restrict__ fv, int* __restrict__ fi, int* __restrict__ mask) {
    const int row  = blockIdx.x;
    const int lane = threadIdx.x;  // 64
    float v0 = -INFINITY, v1 = -INFINITY, v2 = -INFINITY;
    int   i0 = 0x7fffffff, i1 = 0x7fffffff, i2 = 0x7fffffff;
    for (int c = lane; c < NCB; c += 64) {
        const size_t base = ((size_t)row * NCB + c) * 3;
#pragma unroll
        for (int t = 0; t < 3; t++)
            ins3(pv[base + t], pi[base + t], v0, i0, v1, i1, v2, i2);
    }
#pragma unroll
    for (int m = 1; m < 64; m <<= 1) {
        const float w0 = __shfl_xor(v0, m, 64);
        const float w1 = __shfl_xor(v1, m, 64);
        const float w2 = __shfl_xor(v2, m, 64);
        const int   j0 = __shfl_xor(i0, m, 64);
        const int   j1 = __shfl_xor(i1, m, 64);
        const int   j2 = __shfl_xor(i2, m, 64);
        ins3(w0, j0, v0, i0, v1, i1, v2, i2);
        ins3(w1, j1, v0, i0, v1, i1, v2, i2);
        ins3(w2, j2, v0, i0, v1, i1, v2, i2);
    }
    if (lane == 0) {
        fv[row * 3 + 0] = v0; fv[row * 3 + 1] = v1; fv[row * 3 + 2] = v2;
        fi[row * 3 + 0] = i0; fi[row * 3 + 1] = i1; fi[row * 3 + 2] = i2;
        mask[i0] = 1; mask[i1] = 1; mask[i2] = 1;   // idempotent racy stores, fine
    }
}

// ---------- count live latents ----------
__global__ __launch_bounds__(256) void count_live(const int* __restrict__ mask,
                                                  float* __restrict__ outScalar) {
    __shared__ int sd[256];
    const int tid = threadIdx.x;
    int s = 0;
    for (int i = tid; i < HID; i += 256) s += mask[i];
    sd[tid] = s;
    __syncthreads();
    for (int st = 128; st > 0; st >>= 1) {
        if (tid < st) sd[tid] += sd[tid + st];
        __syncthreads();
    }
    if (tid == 0) outScalar[0] = (float)sd[0];
}

// ---------- transpose W_dec [DIM][HID] -> Wt [HID][DIM] so decode gathers are coalesced ----------
__global__ __launch_bounds__(256) void transpose_wdec(const float* __restrict__ W,
                                                      float* __restrict__ Wt) {
    __shared__ float t[32][33];
    const int bx = blockIdx.x;          // along HID (16384/32)
    const int by = blockIdx.y;          // along DIM (768/32)
    const int x  = threadIdx.x & 31;
    const int y  = threadIdx.x >> 5;    // 0..7
#pragma unroll
    for (int i = 0; i < 4; i++) {
        const int d = by * 32 + y + i * 8;
        t[y + i * 8][x] = W[(size_t)d * HID + bx * 32 + x];
    }
    __syncthreads();
#pragma unroll
    for (int i = 0; i < 4; i++) {
        const int h = bx * 32 + y + i * 8;
        Wt[(size_t)h * DIM + by * 32 + x] = t[x][y + i * 8];
    }
}

// ---------- sparse decode: out[b,:] = b_dec + sum_k val_k * Wt[idx_k,:] ----------
__global__ __launch_bounds__(192) void decode_rows(
        const float* __restrict__ fv, const int* __restrict__ fi,
        const float* __restrict__ Wt, const float* __restrict__ bdec,
        float* __restrict__ out) {
    const int row = blockIdx.x;
    const int tid = threadIdx.x;        // 192 threads * float4 = 768
    const float v0 = fv[row * 3 + 0], v1 = fv[row * 3 + 1], v2 = fv[row * 3 + 2];
    const int   i0 = fi[row * 3 + 0], i1 = fi[row * 3 + 1], i2 = fi[row * 3 + 2];
    const int j = tid * 4;
    const float4 b  = *(const float4*)(bdec + j);
    const float4 w0 = *(const float4*)(Wt + (size_t)i0 * DIM + j);
    const float4 w1 = *(const float4*)(Wt + (size_t)i1 * DIM + j);
    const float4 w2 = *(const float4*)(Wt + (size_t)i2 * DIM + j);
    float4 o;
    o.x = b.x + v0 * w0.x + v1 * w1.x + v2 * w2.x;
    o.y = b.y + v0 * w0.y + v1 * w1.y + v2 * w2.y;
    o.z = b.z + v0 * w0.z + v1 * w1.z + v2 * w2.z;
    o.w = b.w + v0 * w0.w + v1 * w1.w + v2 * w2.w;
    *(float4*)(out + (size_t)row * DIM + j) = o;
}

extern "C" void kernel_launch(void* const* d_in, const int* in_sizes, int n_in,
                              void* d_out, int out_size, void* d_ws, size_t ws_size,
                              hipStream_t stream) {
    const float* X    = (const float*)d_in[0];   // [B, DIM]
    const float* Wenc = (const float*)d_in[1];   // [HID, DIM]
    const float* benc = (const float*)d_in[2];   // [HID]
    const float* Wdec = (const float*)d_in[3];   // [DIM, HID]
    const float* bdec = (const float*)d_in[4];   // [DIM]
    float* out = (float*)d_out;                  // [B*DIM] recon + [1] num_live (as float)

    // workspace layout (bytes):
    //   [0, 25165824)           pv  (B*NCB*3 floats)
    //   [25165824, 50331648)    pi  (B*NCB*3 ints)
    //   [0, 50331648)           Wt  (HID*DIM floats) -- REUSES pv+pi after reduce_topk
    //   [50331648, +196608)     fv  (B*3 floats)
    //   [50528256, +196608)     fi  (B*3 ints)
    //   [50724864, +65536)      mask (HID ints)
    char* ws = (char*)d_ws;
    float* pv   = (float*)ws;
    int*   pi   = (int*)(ws + 25165824);
    float* Wt   = (float*)ws;
    float* fv   = (float*)(ws + 50331648);
    int*   fi   = (int*)(ws + 50528256);
    int*   mask = (int*)(ws + 50724864);

    hipMemsetAsync(mask, 0, HID * sizeof(int), stream);

    gemm_topk<<<dim3(NCB, B_ROWS / BM), 256, 0, stream>>>(X, Wenc, benc, pv, pi);
    reduce_topk<<<B_ROWS, 64, 0, stream>>>(pv, pi, fv, fi, mask);
    count_live<<<1, 256, 0, stream>>>(mask, out + (size_t)B_ROWS * DIM);
    // transpose reuses pv/pi memory -> must come after reduce_topk (stream-ordered)
    transpose_wdec<<<dim3(HID / 32, DIM / 32), 256, 0, stream>>>(Wdec, Wt);
    decode_rows<<<B_ROWS, 192, 0, stream>>>(fv, fi, Wt, bdec, out);
}

// Round 3
// 958.998 us; speedup vs baseline: 10.2280x; 5.0889x over previous
//
#include <hip/hip_runtime.h>
#include <cstdint>
#include <cstddef>

#define B_ROWS 16384
#define DIM    768
#define HID    16384
#define NCB    128           // 16384/128 column blocks
#define KSTEPS (DIM / 32)    // 24

typedef __bf16 bf16x8 __attribute__((ext_vector_type(8)));
typedef float  f32x4  __attribute__((ext_vector_type(4)));
typedef unsigned int   u32;
typedef unsigned short u16;

// ---------- helpers ----------
__device__ __forceinline__ u32 umaxu(u32 a, u32 b) { return a > b ? a : b; }
__device__ __forceinline__ u32 uminu(u32 a, u32 b) { return a < b ? a : b; }

// XOR swizzle for LDS 16B-chunk placement: keeps frag ds_read_b128 at free 2-way aliasing
__device__ __forceinline__ int swz(int r) { return (r & 3) ^ ((r >> 2) & 3); }

// fp32 -> bf16 (RNE)
__device__ __forceinline__ u16 f2bf(float f) {
    u32 u = __float_as_uint(f);
    return (u16)((u + 0x7FFFu + ((u >> 16) & 1u)) >> 16);
}

// screening key: monotone-mapped bf16(value) in high 16 bits, latent idx in low 16.
// uint compare == value compare (ties -> larger idx, harmless for screening).
__device__ __forceinline__ u32 pk(float v, int gidx) {
    u32 b = __float_as_uint(v);
    u32 t = b >> 16;
    t ^= (b & 0x80000000u) ? 0xFFFFu : 0x8000u;
    return (t << 16) | (u32)gidx;
}

// async global->LDS, 16B per lane; LDS dest = base + lane*16
__device__ __forceinline__ void gll16(const void* g, void* l) {
    __builtin_amdgcn_global_load_lds(
        (const __attribute__((address_space(1))) unsigned int*)g,
        (__attribute__((address_space(3))) unsigned int*)l, 16, 0, 0);
}

// exact-stage top-3 (tie-break: lower index wins, matching jax.lax.top_k)
__device__ __forceinline__ bool better(float v1, int i1, float v2, int i2) {
    return (v1 > v2) || (v1 == v2 && i1 < i2);
}
__device__ __forceinline__ void ins3(float v, int i,
                                     float& v0, int& i0, float& v1, int& i1,
                                     float& v2, int& i2) {
    if (better(v, i, v2, i2)) {
        v2 = v; i2 = i;
        if (better(v2, i2, v1, i1)) { float tv = v1; int ti = i1; v1 = v2; i1 = i2; v2 = tv; i2 = ti; }
        if (better(v1, i1, v0, i0)) { float tv = v0; int ti = i0; v0 = v1; i0 = i1; v1 = tv; i1 = ti; }
    }
}

// ---------- cast X and W_enc to bf16 ----------
__global__ __launch_bounds__(256) void cast_bf16(const float* __restrict__ X,
                                                 const float* __restrict__ W,
                                                 u16* __restrict__ Xb, u16* __restrict__ Wb) {
    const int n4 = (B_ROWS * DIM) / 4;
    for (int i = blockIdx.x * blockDim.x + threadIdx.x; i < n4; i += gridDim.x * blockDim.x) {
        float4 x = ((const float4*)X)[i];
        float4 w = ((const float4*)W)[i];
        ushort4 xo, wo;
        xo.x = f2bf(x.x); xo.y = f2bf(x.y); xo.z = f2bf(x.z); xo.w = f2bf(x.w);
        wo.x = f2bf(w.x); wo.y = f2bf(w.y); wo.z = f2bf(w.z); wo.w = f2bf(w.w);
        ((ushort4*)Xb)[i] = xo;
        ((ushort4*)Wb)[i] = wo;
    }
}

// ---------- bf16 MFMA GEMM + fused per-(row,128-col-block) top-3 screening ----------
// 128x128 tile, BK=32. 4 waves in 2x2: wave (w>>1) -> row half, (w&1) -> col half, each 64x64.
// pvpi layout: [row][cb][3] packed keys (read-coalesced by the reduce kernel).
__global__ __launch_bounds__(256) void gemm_screen(const u16* __restrict__ Xb,
                                                   const u16* __restrict__ Wb,
                                                   const float* __restrict__ benc,
                                                   u32* __restrict__ pvpi) {
    __shared__ __align__(16) u16 As[128 * 32];
    __shared__ __align__(16) u16 Bs[128 * 32];
    __shared__ u32 sm[4 * 64 * 3];

    // supertile swizzle (16x16 blocks) for L2 reuse of A/B slabs
    const int bid = blockIdx.x;
    const int st = bid >> 8, loc = bid & 255;
    const int rb = (st >> 3) * 16 + (loc >> 4);
    const int cb = (st & 7) * 16 + (loc & 15);
    const int rowBase = rb * 128, colBase = cb * 128;

    const int tid = threadIdx.x;
    const int w = tid >> 6, lane = tid & 63;

    // staging: wave w issues loads q = w*2+i; LDS 16B-position p = q*64+lane;
    // row r = p>>2, swizzled chunk csw = p&3, actual chunk c = csw ^ swz(r)
    const u16* gA[2]; const u16* gB[2]; u16* lA[2]; u16* lB[2];
#pragma unroll
    for (int i = 0; i < 2; i++) {
        const int q = w * 2 + i;
        const int p = q * 64 + lane;
        const int r = p >> 2;
        const int c = (p & 3) ^ swz(r);
        gA[i] = Xb + (size_t)(rowBase + r) * DIM + c * 8;
        gB[i] = Wb + (size_t)(colBase + r) * DIM + c * 8;
        lA[i] = As + q * 512;   // 512 u16 = 1024B per wave-load
        lB[i] = Bs + q * 512;
    }

    // fragment LDS offsets (16B units), k-invariant
    const int j = lane & 15, g = lane >> 4;
    const int wm = (w >> 1) * 64, wn = (w & 1) * 64;
    int aoff[4], boff[4];
#pragma unroll
    for (int t = 0; t < 4; t++) {
        const int m = wm + t * 16 + j;
        aoff[t] = m * 4 + (g ^ swz(m));
        const int n = wn + t * 16 + j;
        boff[t] = n * 4 + (g ^ swz(n));
    }

    f32x4 acc[4][4];
#pragma unroll
    for (int mt = 0; mt < 4; mt++)
#pragma unroll
        for (int nt = 0; nt < 4; nt++) acc[mt][nt] = (f32x4){0.f, 0.f, 0.f, 0.f};

    // prologue: stage tile 0
#pragma unroll
    for (int i = 0; i < 2; i++) { gll16(gA[i], lA[i]); gll16(gB[i], lB[i]); }

    const bf16x8* As8 = (const bf16x8*)As;
    const bf16x8* Bs8 = (const bf16x8*)Bs;

    for (int kk = 0; kk < KSTEPS; ++kk) {
        __syncthreads();                       // tile kk landed in LDS
        bf16x8 aF[4], bF[4];
#pragma unroll
        for (int t = 0; t < 4; t++) { aF[t] = As8[aoff[t]]; bF[t] = Bs8[boff[t]]; }
        __syncthreads();                       // frags in regs; LDS reusable
        if (kk + 1 < KSTEPS) {
            const int o = (kk + 1) * 32;
#pragma unroll
            for (int i = 0; i < 2; i++) { gll16(gA[i] + o, lA[i]); gll16(gB[i] + o, lB[i]); }
        }
#pragma unroll
        for (int mt = 0; mt < 4; mt++)
#pragma unroll
            for (int nt = 0; nt < 4; nt++)
                acc[mt][nt] = __builtin_amdgcn_mfma_f32_16x16x32_bf16(aF[mt], bF[nt], acc[mt][nt], 0, 0, 0);
    }

    // epilogue: bias + packed top-3 per row over this wave's 64 cols
    // C/D layout: col = lane&15 (+nt*16), row = (lane>>4)*4 + reg (+mt*16) [m89]
    float bias[4]; int gcol[4];
#pragma unroll
    for (int nt = 0; nt < 4; nt++) {
        gcol[nt] = colBase + wn + nt * 16 + j;
        bias[nt] = benc[gcol[nt]];
    }

#pragma unroll
    for (int mt = 0; mt < 4; mt++) {
#pragma unroll
        for (int reg = 0; reg < 4; reg++) {
            const u32 k0 = pk(acc[mt][0][reg] + bias[0], gcol[0]);
            const u32 k1 = pk(acc[mt][1][reg] + bias[1], gcol[1]);
            const u32 k2 = pk(acc[mt][2][reg] + bias[2], gcol[2]);
            const u32 k3 = pk(acc[mt][3][reg] + bias[3], gcol[3]);
            // sorted top-3 of 4
            u32 a0 = umaxu(k0, k1), a1 = uminu(k0, k1);
            u32 b0 = umaxu(k2, k3), b1 = uminu(k2, k3);
            u32 x0 = umaxu(a0, b0);
            u32 p = uminu(a0, b0), q = umaxu(a1, b1), r2 = uminu(a1, b1);
            u32 x1 = umaxu(p, q);
            u32 x2 = umaxu(uminu(p, q), r2);
            // butterfly merge across the 16 lanes holding this row
#pragma unroll
            for (int mk = 1; mk < 16; mk <<= 1) {
                const u32 y0 = (u32)__shfl_xor((int)x0, mk, 64);
                const u32 y1 = (u32)__shfl_xor((int)x1, mk, 64);
                const u32 y2 = (u32)__shfl_xor((int)x2, mk, 64);
                const u32 P = uminu(x0, y0), Q = umaxu(x1, y1);
                const u32 R = uminu(x1, y1), S = umaxu(x2, y2);
                const u32 z0 = umaxu(x0, y0);
                const u32 z1 = umaxu(P, Q);
                const u32 z2 = umaxu(umaxu(uminu(P, Q), R), S);
                x0 = z0; x1 = z1; x2 = z2;
            }
            if ((lane & 15) == 0) {
                const int rloc = mt * 16 + g * 4 + reg;
                sm[(w * 64 + rloc) * 3 + 0] = x0;
                sm[(w * 64 + rloc) * 3 + 1] = x1;
                sm[(w * 64 + rloc) * 3 + 2] = x2;
            }
        }
    }
    __syncthreads();
    // merge the two 64-col halves per row, write pvpi[row][cb][3]
    if (tid < 128) {
        const int row = tid;
        const int wp = (row >> 6) * 2, rl = row & 63;
        const u32 A0 = sm[((wp + 0) * 64 + rl) * 3 + 0];
        const u32 A1 = sm[((wp + 0) * 64 + rl) * 3 + 1];
        const u32 A2 = sm[((wp + 0) * 64 + rl) * 3 + 2];
        const u32 B0 = sm[((wp + 1) * 64 + rl) * 3 + 0];
        const u32 B1 = sm[((wp + 1) * 64 + rl) * 3 + 1];
        const u32 B2 = sm[((wp + 1) * 64 + rl) * 3 + 2];
        const u32 P = uminu(A0, B0), Q = umaxu(A1, B1);
        const u32 R = uminu(A1, B1), S = umaxu(A2, B2);
        const u32 z0 = umaxu(A0, B0);
        const u32 z1 = umaxu(P, Q);
        const u32 z2 = umaxu(umaxu(uminu(P, Q), R), S);
        const size_t base = ((size_t)(rowBase + row) * NCB + cb) * 3;
        pvpi[base + 0] = z0; pvpi[base + 1] = z1; pvpi[base + 2] = z2;
    }
}

// ---------- reduce 384 screening keys -> top-16 candidates -> exact fp32 recheck ----------
__global__ __launch_bounds__(256) void reduce_recheck(
        const u32* __restrict__ pvpi, const float* __restrict__ X,
        const float* __restrict__ Wenc, const float* __restrict__ benc,
        float* __restrict__ fv, int* __restrict__ fi, int* __restrict__ mask) {
    const int wid = threadIdx.x >> 6, lane = threadIdx.x & 63;
    const int row = blockIdx.x * 4 + wid;

    const u32* p = pvpi + (size_t)row * (NCB * 3);
    u32 k[6];
#pragma unroll
    for (int t = 0; t < 6; t++) k[t] = p[t * 64 + lane];

    // extract top-16 keys (keys unique: latent idx in low bits)
    u32 cand[16];
#pragma unroll
    for (int it = 0; it < 16; ++it) {
        u32 m = k[0];
#pragma unroll
        for (int t = 1; t < 6; t++) m = umaxu(m, k[t]);
#pragma unroll
        for (int mk = 1; mk < 64; mk <<= 1) m = umaxu(m, (u32)__shfl_xor((int)m, mk, 64));
        cand[it] = m;
#pragma unroll
        for (int t = 0; t < 6; t++) if (k[t] == m) k[t] = 0;
    }

    // exact fp32 recheck: lane covers dims [lane*12, lane*12+12)
    const float4* xp = (const float4*)(X + (size_t)row * DIM) + lane * 3;
    const float4 x0 = xp[0], x1 = xp[1], x2 = xp[2];

    float v0 = -INFINITY, v1 = -INFINITY, v2 = -INFINITY;
    int   i0 = 0x7fffffff, i1 = 0x7fffffff, i2 = 0x7fffffff;
#pragma unroll
    for (int it = 0; it < 16; ++it) {
        const int ci = (int)(cand[it] & 0xFFFFu);
        const float4* wq = (const float4*)(Wenc + (size_t)ci * DIM) + lane * 3;
        const float4 w0 = wq[0], w1 = wq[1], w2 = wq[2];
        float s = x0.x * w0.x;
        s = fmaf(x0.y, w0.y, s); s = fmaf(x0.z, w0.z, s); s = fmaf(x0.w, w0.w, s);
        s = fmaf(x1.x, w1.x, s); s = fmaf(x1.y, w1.y, s); s = fmaf(x1.z, w1.z, s);
        s = fmaf(x1.w, w1.w, s); s = fmaf(x2.x, w2.x, s); s = fmaf(x2.y, w2.y, s);
        s = fmaf(x2.z, w2.z, s); s = fmaf(x2.w, w2.w, s);
#pragma unroll
        for (int mk = 1; mk < 64; mk <<= 1) s += __shfl_xor(s, mk, 64);
        const float val = s + benc[ci];
        ins3(val, ci, v0, i0, v1, i1, v2, i2);
    }
    if (lane == 0) {
        fv[row * 3 + 0] = v0; fv[row * 3 + 1] = v1; fv[row * 3 + 2] = v2;
        fi[row * 3 + 0] = i0; fi[row * 3 + 1] = i1; fi[row * 3 + 2] = i2;
        mask[i0] = 1; mask[i1] = 1; mask[i2] = 1;
    }
}

// ---------- count live latents ----------
__global__ __launch_bounds__(256) void count_live(const int* __restrict__ mask,
                                                  float* __restrict__ outScalar) {
    __shared__ int sd[256];
    const int tid = threadIdx.x;
    int s = 0;
    for (int i = tid; i < HID; i += 256) s += mask[i];
    sd[tid] = s;
    __syncthreads();
    for (int st = 128; st > 0; st >>= 1) {
        if (tid < st) sd[tid] += sd[tid + st];
        __syncthreads();
    }
    if (tid == 0) outScalar[0] = (float)sd[0];
}

// ---------- transpose W_dec [DIM][HID] -> Wt [HID][DIM] ----------
__global__ __launch_bounds__(256) void transpose_wdec(const float* __restrict__ W,
                                                      float* __restrict__ Wt) {
    __shared__ float t[32][33];
    const int bx = blockIdx.x;
    const int by = blockIdx.y;
    const int x = threadIdx.x & 31;
    const int y = threadIdx.x >> 5;
#pragma unroll
    for (int i = 0; i < 4; i++) {
        const int d = by * 32 + y + i * 8;
        t[y + i * 8][x] = W[(size_t)d * HID + bx * 32 + x];
    }
    __syncthreads();
#pragma unroll
    for (int i = 0; i < 4; i++) {
        const int h = bx * 32 + y + i * 8;
        Wt[(size_t)h * DIM + by * 32 + x] = t[x][y + i * 8];
    }
}

// ---------- sparse decode ----------
__global__ __launch_bounds__(192) void decode_rows(
        const float* __restrict__ fv, const int* __restrict__ fi,
        const float* __restrict__ Wt, const float* __restrict__ bdec,
        float* __restrict__ out) {
    const int row = blockIdx.x;
    const int tid = threadIdx.x;
    const float v0 = fv[row * 3 + 0], v1 = fv[row * 3 + 1], v2 = fv[row * 3 + 2];
    const int   i0 = fi[row * 3 + 0], i1 = fi[row * 3 + 1], i2 = fi[row * 3 + 2];
    const int jj = tid * 4;
    const float4 b  = *(const float4*)(bdec + jj);
    const float4 w0 = *(const float4*)(Wt + (size_t)i0 * DIM + jj);
    const float4 w1 = *(const float4*)(Wt + (size_t)i1 * DIM + jj);
    const float4 w2 = *(const float4*)(Wt + (size_t)i2 * DIM + jj);
    float4 o;
    o.x = b.x + v0 * w0.x + v1 * w1.x + v2 * w2.x;
    o.y = b.y + v0 * w0.y + v1 * w1.y + v2 * w2.y;
    o.z = b.z + v0 * w0.z + v1 * w1.z + v2 * w2.z;
    o.w = b.w + v0 * w0.w + v1 * w1.w + v2 * w2.w;
    *(float4*)(out + (size_t)row * DIM + jj) = o;
}

extern "C" void kernel_launch(void* const* d_in, const int* in_sizes, int n_in,
                              void* d_out, int out_size, void* d_ws, size_t ws_size,
                              hipStream_t stream) {
    const float* X    = (const float*)d_in[0];   // [B, DIM]
    const float* Wenc = (const float*)d_in[1];   // [HID, DIM]
    const float* benc = (const float*)d_in[2];   // [HID]
    const float* Wdec = (const float*)d_in[3];   // [DIM, HID]
    const float* bdec = (const float*)d_in[4];   // [DIM]
    float* out = (float*)d_out;                  // [B*DIM] recon + [1] num_live

    // workspace layout (bytes):
    //   [0, 25165824)            Xb bf16        -- dead after gemm
    //   [25165824, 50331648)     Wb bf16        -- dead after gemm
    //   [0, 50331648)            Wt fp32        -- REUSES Xb+Wb after gemm
    //   [50331648, 75497472)     pvpi packed keys [B][128][3]
    //   [75497472, +196608)      fv
    //   [75694080, +196608)      fi
    //   [75890688, +65536)       mask
    char* ws = (char*)d_ws;
    u16*   Xb   = (u16*)ws;
    u16*   Wb   = (u16*)(ws + 25165824);
    float* Wt   = (float*)ws;
    u32*   pvpi = (u32*)(ws + 50331648);
    float* fv   = (float*)(ws + 75497472);
    int*   fi   = (int*)(ws + 75694080);
    int*   mask = (int*)(ws + 75890688);

    hipMemsetAsync(mask, 0, HID * sizeof(int), stream);

    cast_bf16<<<3072, 256, 0, stream>>>(X, Wenc, Xb, Wb);
    gemm_screen<<<16384, 256, 0, stream>>>(Xb, Wb, benc, pvpi);
    reduce_recheck<<<B_ROWS / 4, 256, 0, stream>>>(pvpi, X, Wenc, benc, fv, fi, mask);
    count_live<<<1, 256, 0, stream>>>(mask, out + (size_t)B_ROWS * DIM);
    // transpose overwrites Xb/Wb (dead after gemm)
    transpose_wdec<<<dim3(HID / 32, DIM / 32), 256, 0, stream>>>(Wdec, Wt);
    decode_rows<<<B_ROWS, 192, 0, stream>>>(fv, fi, Wt, bdec, out);
}